// Round 3
// baseline (629.014 us; speedup 1.0000x reference)
//
#include <hip/hip_runtime.h>

#define BATCH 262144
#define NH 64     // hidden width
#define NIN 64    // 2*D input width
#define ND 32     // q-dim (output width)

// ---------------------------------------------------------------------------
// Prep (re-runs every launch): W2T[j][i] = W2[i][j] in global ws, so the main
// kernel can stage it into LDS with conflict-free linear float4 copies.
// ---------------------------------------------------------------------------
__global__ void lnn_prep(const float* __restrict__ W2, float* __restrict__ W2T) {
    int t = blockIdx.x * blockDim.x + threadIdx.x;
    if (t < NH * NH) {
        int i = t >> 6, j = t & 63;          // W2[i][j], row i contiguous
        W2T[j * NH + i] = W2[t];
    }
}

// ---------------------------------------------------------------------------
// One thread = one sample. Weights live in LDS; every weight read is a
// uniform-address broadcast (no bank conflicts, deep ds pipelining).
// MASK PATH: bit-identical fp32 ascending-i single-accumulator fmaf chains,
// bias added once after the chain (matches numpy sgemm + `+b`). Unchanged
// arithmetic vs the passing round-2 kernel.
// VALUE PATH: fp32, tolerance is 2% of absmax.
// ---------------------------------------------------------------------------
__global__ __launch_bounds__(256, 4) void lnn_main(
        const float* __restrict__ X,
        const float* __restrict__ W1,  const float* __restrict__ b1,
        const float* __restrict__ W2T, const float* __restrict__ b2,
        const float* __restrict__ W3,
        float* __restrict__ out) {
    __shared__ float sW1[NIN * NH];    // [i][j], row i contiguous (16 KB)
    __shared__ float sW2T[NH * NH];    // [j][i], row j contiguous (16 KB)
    __shared__ float sb1[NH], sb2[NH], sw3[NH];

    const int tid = threadIdx.x;
    {   // cooperative stage: 2x 4096 floats as float4 (linear, conflict-free)
        const float4* gW1 = reinterpret_cast<const float4*>(W1);
        const float4* gW2 = reinterpret_cast<const float4*>(W2T);
        float4* l1 = reinterpret_cast<float4*>(sW1);
        float4* l2 = reinterpret_cast<float4*>(sW2T);
#pragma unroll
        for (int v = 0; v < 4; ++v) {
            l1[v * 256 + tid] = gW1[v * 256 + tid];
            l2[v * 256 + tid] = gW2[v * 256 + tid];
        }
        if (tid < NH) { sb1[tid] = b1[tid]; sb2[tid] = b2[tid]; sw3[tid] = W3[tid]; }
    }
    __syncthreads();

    const int s = blockIdx.x * blockDim.x + tid;
    const float* __restrict__ xp = X + (size_t)s * NIN;

    // ---- phase A: z1 = x @ W1 (+b1 after), relu, mask. j tiled in halves
    // of 32 so acc[] stays small (VGPR <= 128 -> 4 waves/SIMD).
    float h[NH];
    unsigned int r1lo = 0, r1hi = 0;
#pragma unroll
    for (int jh = 0; jh < 2; ++jh) {
        float acc[32];
#pragma unroll
        for (int j = 0; j < 32; ++j) acc[j] = 0.0f;
#pragma unroll 4
        for (int ig = 0; ig < NIN / 4; ++ig) {         // float4 x loads (L1-hot)
            const float4 xv = reinterpret_cast<const float4*>(xp)[ig];
            const float xs[4] = {xv.x, xv.y, xv.z, xv.w};
#pragma unroll
            for (int ii = 0; ii < 4; ++ii) {
                const float* wr = sW1 + (ig * 4 + ii) * NH + jh * 32;
#pragma unroll
                for (int j = 0; j < 32; ++j)
                    acc[j] = fmaf(xs[ii], wr[j], acc[j]);   // ascending i chain
            }
        }
        unsigned int m = 0;
#pragma unroll
        for (int j = 0; j < 32; ++j) {
            const float z1 = acc[j] + sb1[jh * 32 + j];    // one rounded add
            if (z1 > 0.0f) m |= (1u << j);
            h[jh * 32 + j] = fmaxf(z1, 0.0f);
        }
        if (jh == 0) r1lo = m; else r1hi = m;
    }

    // ---- phase B1: z2_j = (h . W2T[j][:]) + b2_j; sign bits only.
    // 4 independent single-accumulator ascending-i chains at a time.
    unsigned int r2lo = 0, r2hi = 0;
    for (int jg = 0; jg < NH / 4; ++jg) {
        const float* q0 = sW2T + (jg * 4 + 0) * NH;
        const float* q1 = sW2T + (jg * 4 + 1) * NH;
        const float* q2 = sW2T + (jg * 4 + 2) * NH;
        const float* q3 = sW2T + (jg * 4 + 3) * NH;
        float p0 = 0.f, p1 = 0.f, p2 = 0.f, p3 = 0.f;
#pragma unroll
        for (int i = 0; i < NH; ++i) {
            p0 = fmaf(h[i], q0[i], p0);
            p1 = fmaf(h[i], q1[i], p1);
            p2 = fmaf(h[i], q2[i], p2);
            p3 = fmaf(h[i], q3[i], p3);
        }
        const int j0 = jg * 4;
        unsigned int bits = 0;
        if (p0 + sb2[j0 + 0] > 0.0f) bits |= 1u;
        if (p1 + sb2[j0 + 1] > 0.0f) bits |= 2u;
        if (p2 + sb2[j0 + 2] > 0.0f) bits |= 4u;
        if (p3 + sb2[j0 + 3] > 0.0f) bits |= 8u;
        if (j0 < 32) r2lo |= bits << j0; else r2hi |= bits << (j0 - 32);
    }
    // h dead from here.

    // ---- phase B2 (values): t_i = sum_{j: r2_j} W2[i,j]*w3_j
    float t_[NH];
#pragma unroll
    for (int i = 0; i < NH; ++i) t_[i] = 0.0f;

    for (int j = 0; j < NH; ++j) {
        const bool mb = (j < 32) ? ((r2lo >> j) & 1u) : ((r2hi >> (j - 32)) & 1u);
        const float ms = mb ? sw3[j] : 0.0f;               // fold w3 here (no Mt)
        const float* mr = sW2T + j * NH;
#pragma unroll
        for (int i = 0; i < NH; ++i) t_[i] = fmaf(ms, mr[i], t_[i]);
    }

    // u = r1 .* t
#pragma unroll
    for (int i = 0; i < NH; ++i) {
        const bool mb = (i < 32) ? ((r1lo >> i) & 1u) : ((r1hi >> (i - 32)) & 1u);
        t_[i] = mb ? t_[i] : 0.0f;
    }

    // ---- phase C (values): out_k = -W1[k,:] . u, k = 0..31; float4 stores
    float* __restrict__ op = out + (size_t)s * ND;
    for (int kq = 0; kq < ND / 4; ++kq) {
        float a[4];
#pragma unroll
        for (int kk = 0; kk < 4; ++kk) {
            const float* wr = sW1 + (kq * 4 + kk) * NH;    // W1 row k (k<32)
            float v0 = 0.f, v1 = 0.f;
#pragma unroll
            for (int i = 0; i < NH; i += 2) {
                v0 = fmaf(wr[i],     t_[i],     v0);
                v1 = fmaf(wr[i + 1], t_[i + 1], v1);
            }
            a[kk] = -(v0 + v1);
        }
        float4 ov;
        ov.x = a[0]; ov.y = a[1]; ov.z = a[2]; ov.w = a[3];
        reinterpret_cast<float4*>(op)[kq] = ov;
    }
}

extern "C" void kernel_launch(void* const* d_in, const int* in_sizes, int n_in,
                              void* d_out, int out_size, void* d_ws, size_t ws_size,
                              hipStream_t stream) {
    const float* X  = (const float*)d_in[0];
    const float* W1 = (const float*)d_in[1];
    const float* b1 = (const float*)d_in[2];
    const float* W2 = (const float*)d_in[3];
    const float* b2 = (const float*)d_in[4];
    const float* W3 = (const float*)d_in[5];
    // d_in[6] = b3: does not affect gradients.
    float* out = (float*)d_out;

    float* W2T = (float*)d_ws;            // 16384 B

    lnn_prep<<<16, 256, 0, stream>>>(W2, W2T);
    lnn_main<<<BATCH / 256, 256, 0, stream>>>(X, W1, b1, W2T, b2, W3, out);
}

// Round 4
// 447.513 us; speedup vs baseline: 1.4056x; 1.4056x over previous
//
#include <hip/hip_runtime.h>

#define BATCH 262144
#define NH 64     // hidden width
#define NIN 64    // 2*D input width
#define ND 32     // q-dim (output width)

// ---------------------------------------------------------------------------
// Prep (re-runs every launch): W2T[j][i] = W2[i][j] in global ws, so the main
// kernel can stage it into LDS with coalesced linear float4 copies.
// ---------------------------------------------------------------------------
__global__ void lnn_prep(const float* __restrict__ W2, float* __restrict__ W2T) {
    int t = blockIdx.x * blockDim.x + threadIdx.x;
    if (t < NH * NH) {
        int i = t >> 6, j = t & 63;          // W2[i][j], row i contiguous
        W2T[j * NH + i] = W2[t];
    }
}

// ---------------------------------------------------------------------------
// One thread = one sample. Weights in LDS; every weight read is a
// wave-uniform broadcast (same address on all 64 lanes -> no bank conflict).
// MASK PATH: bit-identical to the passing round-2 kernel: fp32 ascending-i
// single-accumulator fmaf chains, bias added once after the chain.
// VALUE PATH: fp32 (tolerance is 2% of absmax).
// NO min-waves launch bound: round 3 proved it forces VGPR=64 + mass spill.
// Peak live state here is ~85 floats (acc[64] -> h[64] -> t_[64] reuse).
// ---------------------------------------------------------------------------
__global__ __launch_bounds__(256) void lnn_main(
        const float* __restrict__ X,
        const float* __restrict__ W1,  const float* __restrict__ b1,
        const float* __restrict__ W2T, const float* __restrict__ b2,
        const float* __restrict__ W3,
        float* __restrict__ out) {
    __shared__ float sW1[NIN * NH];    // [i][j], row i contiguous (16 KB)
    __shared__ float sW2T[NH * NH];    // [j][i], row j contiguous (16 KB)
    __shared__ float sb1[NH], sb2[NH], sw3[NH];

    const int tid = threadIdx.x;
    {   // cooperative stage: 2x 4096 floats as float4 (coalesced, conflict-free)
        const float4* gW1 = reinterpret_cast<const float4*>(W1);
        const float4* gW2 = reinterpret_cast<const float4*>(W2T);
        float4* l1 = reinterpret_cast<float4*>(sW1);
        float4* l2 = reinterpret_cast<float4*>(sW2T);
#pragma unroll
        for (int v = 0; v < 4; ++v) {
            l1[v * 256 + tid] = gW1[v * 256 + tid];
            l2[v * 256 + tid] = gW2[v * 256 + tid];
        }
        if (tid < NH) { sb1[tid] = b1[tid]; sb2[tid] = b2[tid]; sw3[tid] = W3[tid]; }
    }
    __syncthreads();

    const int s = blockIdx.x * blockDim.x + tid;
    const float* __restrict__ xp = X + (size_t)s * NIN;

    // ---- phase A: z1 = x @ W1 (+b1 after), relu, mask. acc[64] untiled.
    float acc[NH];
#pragma unroll
    for (int j = 0; j < NH; ++j) acc[j] = 0.0f;

    for (int ig = 0; ig < NIN / 4; ++ig) {            // float4 x loads
        const float4 xv = reinterpret_cast<const float4*>(xp)[ig];
        const float xs[4] = {xv.x, xv.y, xv.z, xv.w};
#pragma unroll
        for (int ii = 0; ii < 4; ++ii) {
            const float* wr = sW1 + (ig * 4 + ii) * NH;
#pragma unroll
            for (int j = 0; j < NH; ++j)
                acc[j] = fmaf(xs[ii], wr[j], acc[j]);     // ascending-i chain
        }
    }

    // z1 = acc + b1 (one rounded add AFTER the chain, like numpy), relu, mask.
    // h reuses acc in place.
    unsigned int r1lo = 0, r1hi = 0;
#pragma unroll
    for (int j = 0; j < NH; ++j) {
        const float z1 = acc[j] + sb1[j];
        if (j < 32) { if (z1 > 0.0f) r1lo |= (1u << j); }
        else        { if (z1 > 0.0f) r1hi |= (1u << (j - 32)); }
        acc[j] = fmaxf(z1, 0.0f);                      // h[j]
    }

    // ---- phase B1: z2_j = (h . W2T[j][:]) + b2_j; sign bits only.
    // 4 independent single-accumulator ascending-i chains at a time.
    unsigned int r2lo = 0, r2hi = 0;
    for (int jg = 0; jg < NH / 4; ++jg) {
        const float* q0 = sW2T + (jg * 4 + 0) * NH;
        const float* q1 = sW2T + (jg * 4 + 1) * NH;
        const float* q2 = sW2T + (jg * 4 + 2) * NH;
        const float* q3 = sW2T + (jg * 4 + 3) * NH;
        float p0 = 0.f, p1 = 0.f, p2 = 0.f, p3 = 0.f;
#pragma unroll
        for (int i = 0; i < NH; ++i) {
            p0 = fmaf(acc[i], q0[i], p0);
            p1 = fmaf(acc[i], q1[i], p1);
            p2 = fmaf(acc[i], q2[i], p2);
            p3 = fmaf(acc[i], q3[i], p3);
        }
        const int j0 = jg * 4;
        unsigned int bits = 0;
        if (p0 + sb2[j0 + 0] > 0.0f) bits |= 1u;
        if (p1 + sb2[j0 + 1] > 0.0f) bits |= 2u;
        if (p2 + sb2[j0 + 2] > 0.0f) bits |= 4u;
        if (p3 + sb2[j0 + 3] > 0.0f) bits |= 8u;
        if (j0 < 32) r2lo |= bits << j0; else r2hi |= bits << (j0 - 32);
    }
    // h (acc) dead from here.

    // ---- phase B2 (values): t_i = sum_{j: r2_j} W2[i,j]*w3_j. t_ reuses acc.
#pragma unroll
    for (int i = 0; i < NH; ++i) acc[i] = 0.0f;

    for (int j = 0; j < NH; ++j) {
        const bool mb = (j < 32) ? ((r2lo >> j) & 1u) : ((r2hi >> (j - 32)) & 1u);
        const float ms = mb ? sw3[j] : 0.0f;           // fold w3 (no Mt array)
        const float* mr = sW2T + j * NH;
#pragma unroll
        for (int i = 0; i < NH; ++i) acc[i] = fmaf(ms, mr[i], acc[i]);
    }

    // u = r1 .* t
#pragma unroll
    for (int i = 0; i < NH; ++i) {
        const bool mb = (i < 32) ? ((r1lo >> i) & 1u) : ((r1hi >> (i - 32)) & 1u);
        acc[i] = mb ? acc[i] : 0.0f;
    }

    // ---- phase C (values): out_k = -W1[k,:] . u, k = 0..31; float4 stores
    float* __restrict__ op = out + (size_t)s * ND;
    for (int kq = 0; kq < ND / 4; ++kq) {
        float a[4];
#pragma unroll
        for (int kk = 0; kk < 4; ++kk) {
            const float* wr = sW1 + (kq * 4 + kk) * NH;    // W1 row k (k<32)
            float v0 = 0.f, v1 = 0.f;
#pragma unroll
            for (int i = 0; i < NH; i += 2) {
                v0 = fmaf(wr[i],     acc[i],     v0);
                v1 = fmaf(wr[i + 1], acc[i + 1], v1);
            }
            a[kk] = -(v0 + v1);
        }
        float4 ov;
        ov.x = a[0]; ov.y = a[1]; ov.z = a[2]; ov.w = a[3];
        reinterpret_cast<float4*>(op)[kq] = ov;
    }
}

extern "C" void kernel_launch(void* const* d_in, const int* in_sizes, int n_in,
                              void* d_out, int out_size, void* d_ws, size_t ws_size,
                              hipStream_t stream) {
    const float* X  = (const float*)d_in[0];
    const float* W1 = (const float*)d_in[1];
    const float* b1 = (const float*)d_in[2];
    const float* W2 = (const float*)d_in[3];
    const float* b2 = (const float*)d_in[4];
    const float* W3 = (const float*)d_in[5];
    // d_in[6] = b3: does not affect gradients.
    float* out = (float*)d_out;

    float* W2T = (float*)d_ws;            // 16384 B

    lnn_prep<<<16, 256, 0, stream>>>(W2, W2T);
    lnn_main<<<BATCH / 256, 256, 0, stream>>>(X, W1, b1, W2T, b2, W3, out);
}

// Round 5
// 374.350 us; speedup vs baseline: 1.6803x; 1.1954x over previous
//
#include <hip/hip_runtime.h>

#define BATCH 262144
#define NH 64     // hidden width
#define NIN 64    // 2*D input width
#define ND 32     // q-dim (output width)
#define TPB 128

// ---------------------------------------------------------------------------
// Prep (re-runs every launch): W2T[j][i] = W2[i][j]; W1T[j][k] = W1[k][j] k<32.
// ---------------------------------------------------------------------------
__global__ void lnn_prep(const float* __restrict__ W2, const float* __restrict__ W1,
                         float* __restrict__ W2T, float* __restrict__ W1T) {
    int t = blockIdx.x * blockDim.x + threadIdx.x;
    if (t < NH * NH) {
        int i = t >> 6, j = t & 63;      // W2[i][j], row i contiguous
        W2T[j * NH + i] = W2[t];
    }
    if (t < ND * NH) {                   // k = t>>6 (<32), j = t&63
        int k = t >> 6, j = t & 63;
        W1T[j * ND + k] = W1[k * NH + j];
    }
}

// ---------------------------------------------------------------------------
// One thread = one sample. Weights via wave-uniform loads -> scalar (s_load)
// pipe, interleaved with FMAs inside small loops (I$-resident). LDS holds only
// the per-thread 64-float h/u row, rotate-swizzled (i+lane)&63 so每 access is
// per-lane-distinct (2 lanes/bank = free). Zero LDS traffic for weights.
// MASK PATH: bit-identical to the passing round-2 kernel (fp32 ascending-i
// single-accumulator fmaf chains, one bias add after the chain).
// VALUE PATH: fp32 (tolerance is 2% of absmax).
// ---------------------------------------------------------------------------
__global__ __launch_bounds__(TPB) void lnn_main(
        const float* __restrict__ X,
        const float* __restrict__ W1, const float* __restrict__ b1,
        const float* __restrict__ W2, const float* __restrict__ b2,
        const float* __restrict__ W3,
        const float* __restrict__ W2T, const float* __restrict__ W1T,
        float* __restrict__ out) {
    __shared__ float hbuf[TPB * NH];        // 32 KB: per-thread 64-float row

    const int tid = threadIdx.x;
    const int s = blockIdx.x * TPB + tid;
    const float* __restrict__ xp = X + (size_t)s * NIN;
    float* __restrict__ hrow = hbuf + tid * NH;
    const int rot = tid & 63;               // rotate swizzle -> no bank conflicts

    // ---- phase A: z1 = x @ W1 (ascending-i single-acc chains, 64 j's) ----
    float acc[NH];
#pragma unroll
    for (int j = 0; j < NH; ++j) acc[j] = 0.f;

#pragma unroll 1
    for (int ig = 0; ig < NIN / 4; ++ig) {
        const float4 xv = reinterpret_cast<const float4*>(xp)[ig];
        const float xs[4] = {xv.x, xv.y, xv.z, xv.w};
#pragma unroll
        for (int ii = 0; ii < 4; ++ii) {
            const float* __restrict__ wr = W1 + (ig * 4 + ii) * NH;  // uniform
#pragma unroll
            for (int j = 0; j < NH; ++j)
                acc[j] = fmaf(xs[ii], wr[j], acc[j]);
        }
    }

    // epilogue: z1 = acc + b1 (ONE rounded add, like numpy), mask, h -> LDS
    unsigned r1lo = 0u, r1hi = 0u;
#pragma unroll
    for (int j = 0; j < NH; ++j) {
        const float z1 = acc[j] + b1[j];
        if (j < 32) { if (z1 > 0.f) r1lo |= (1u << j); }
        else        { if (z1 > 0.f) r1hi |= (1u << (j - 32)); }
        hrow[(j + rot) & 63] = fmaxf(z1, 0.f);
    }
    // acc dead -> VGPR pressure drops for B1.

    // ---- phase B1: z2_j = (h . W2[:,j]) + b2_j; sign bits only.
    // j in two halves of 32; each zacc[j] is a single ascending-i fmaf chain.
    unsigned r2lo = 0u, r2hi = 0u;
#pragma unroll 1
    for (int jh = 0; jh < 2; ++jh) {
        float zacc[32];
#pragma unroll
        for (int j = 0; j < 32; ++j) zacc[j] = 0.f;
#pragma unroll 2
        for (int i = 0; i < NH; ++i) {
            const float hi = hrow[(i + rot) & 63];
            const float* __restrict__ wr = W2 + i * NH + jh * 32;    // uniform
#pragma unroll
            for (int j = 0; j < 32; ++j)
                zacc[j] = fmaf(hi, wr[j], zacc[j]);
        }
        unsigned m = 0u;
#pragma unroll
        for (int j = 0; j < 32; ++j)
            if (zacc[j] + b2[jh * 32 + j] > 0.f) m |= (1u << j);
        if (jh == 0) r2lo = m; else r2hi = m;
    }

    // ---- phase B2 (values): t_j = sum_{j2: r2} w3_j2 * W2[j][j2] ----
    float t_[NH];
#pragma unroll
    for (int j = 0; j < NH; ++j) t_[j] = 0.f;

#pragma unroll 1
    for (int j2 = 0; j2 < 32; ++j2) {
        const float ms = ((r2lo >> j2) & 1u) ? W3[j2] : 0.f;
        const float* __restrict__ wr = W2T + j2 * NH;                // uniform
#pragma unroll
        for (int j = 0; j < NH; ++j) t_[j] = fmaf(ms, wr[j], t_[j]);
    }
#pragma unroll 1
    for (int j2 = 32; j2 < 64; ++j2) {
        const float ms = ((r2hi >> (j2 - 32)) & 1u) ? W3[j2] : 0.f;
        const float* __restrict__ wr = W2T + j2 * NH;                // uniform
#pragma unroll
        for (int j = 0; j < NH; ++j) t_[j] = fmaf(ms, wr[j], t_[j]);
    }

    // u = r1 .* t -> LDS (reuse hrow; h is dead)
#pragma unroll
    for (int j = 0; j < NH; ++j) {
        const bool mb = (j < 32) ? ((r1lo >> j) & 1u) : ((r1hi >> (j - 32)) & 1u);
        hrow[(j + rot) & 63] = mb ? t_[j] : 0.f;
    }
    // t_ dead.

    // ---- phase C (values): out_k = -sum_j2 u_j2 * W1[k][j2] ----
    float o[ND];
#pragma unroll
    for (int k = 0; k < ND; ++k) o[k] = 0.f;

#pragma unroll 1
    for (int j2 = 0; j2 < NH; ++j2) {
        const float u = hrow[(j2 + rot) & 63];
        const float* __restrict__ wr = W1T + j2 * ND;                // uniform
#pragma unroll
        for (int k = 0; k < ND; ++k) o[k] = fmaf(u, wr[k], o[k]);
    }

    float* __restrict__ op = out + (size_t)s * ND;
#pragma unroll
    for (int kq = 0; kq < ND / 4; ++kq) {
        float4 ov;
        ov.x = -o[kq * 4 + 0]; ov.y = -o[kq * 4 + 1];
        ov.z = -o[kq * 4 + 2]; ov.w = -o[kq * 4 + 3];
        reinterpret_cast<float4*>(op)[kq] = ov;
    }
}

extern "C" void kernel_launch(void* const* d_in, const int* in_sizes, int n_in,
                              void* d_out, int out_size, void* d_ws, size_t ws_size,
                              hipStream_t stream) {
    const float* X  = (const float*)d_in[0];
    const float* W1 = (const float*)d_in[1];
    const float* b1 = (const float*)d_in[2];
    const float* W2 = (const float*)d_in[3];
    const float* b2 = (const float*)d_in[4];
    const float* W3 = (const float*)d_in[5];
    // d_in[6] = b3: does not affect gradients.
    float* out = (float*)d_out;

    char* ws = (char*)d_ws;
    float* W2T = (float*)(ws);            // 16384 B
    float* W1T = (float*)(ws + 16384);    //  8192 B

    lnn_prep<<<16, 256, 0, stream>>>(W2, W1, W2T, W1T);
    lnn_main<<<BATCH / TPB, TPB, 0, stream>>>(X, W1, b1, W2, b2, W3, W2T, W1T, out);
}

// Round 6
// 362.656 us; speedup vs baseline: 1.7345x; 1.0322x over previous
//
#include <hip/hip_runtime.h>

#define BATCH 262144
#define NH 64     // hidden width
#define NIN 64    // 2*D input width
#define ND 32     // q-dim (output width)
#define TPB 256

// ---------------------------------------------------------------------------
// Prep (re-runs every launch): W2T[j][i] = W2[i][j] (row j = column j of W2).
// ---------------------------------------------------------------------------
__global__ void lnn_prep(const float* __restrict__ W2, float* __restrict__ W2T) {
    int t = blockIdx.x * blockDim.x + threadIdx.x;
    if (t < NH * NH) {
        int i = t >> 6, j = t & 63;          // W2[i][j], row i contiguous
        W2T[j * NH + i] = W2[t];
    }
}

// ---------------------------------------------------------------------------
// One thread = one sample. NO LDS. All weight reads are wave-uniform row
// streams (scalar-pipe friendly); per-thread state lives in registers with
// STATIC indexing only:
//   A:  acc[64] (inner j unrolled), becomes h in place
//   B1: per-j single-scalar accumulators (4 chains/group, j is outer loop)
//   B2: t_[64] (inner j unrolled, outer j2 real loop)
//   C:  per-k single-scalar accumulators (4 chains/group, k is outer loop)
// Peak live ~100 VGPR -> 4 waves/SIMD; all outer loops `unroll 1` (I$-small).
// MASK PATH bit-identical to the round-2/round-5 passing kernels: fp32
// ascending-i single-accumulator fmaf chains; ONE bias add after the chain.
// ---------------------------------------------------------------------------
__global__ __launch_bounds__(TPB) void lnn_main(
        const float* __restrict__ X,
        const float* __restrict__ W1,  const float* __restrict__ b1,
        const float* __restrict__ W2T, const float* __restrict__ b2,
        const float* __restrict__ W3,
        float* __restrict__ out) {
    const int s = blockIdx.x * TPB + threadIdx.x;
    const float* __restrict__ xp = X + (size_t)s * NIN;

    // ---- phase A: z1 = x @ W1 (64 ascending-i single-acc chains) ----
    float acc[NH];
#pragma unroll
    for (int j = 0; j < NH; ++j) acc[j] = 0.f;

#pragma unroll 1
    for (int ig = 0; ig < NIN / 4; ++ig) {
        const float4 xv = reinterpret_cast<const float4*>(xp)[ig];
        const float xs[4] = {xv.x, xv.y, xv.z, xv.w};
#pragma unroll
        for (int ii = 0; ii < 4; ++ii) {
            const float* __restrict__ wr = W1 + (ig * 4 + ii) * NH;  // uniform
#pragma unroll
            for (int j = 0; j < NH; ++j)
                acc[j] = fmaf(xs[ii], wr[j], acc[j]);
        }
    }

    // z1 = acc + b1 (ONE rounded add AFTER the chain, like numpy); mask; relu
    // in place (acc becomes h).
    unsigned r1lo = 0u, r1hi = 0u;
#pragma unroll
    for (int j = 0; j < NH; ++j) {
        const float z1 = acc[j] + b1[j];
        if (j < 32) { if (z1 > 0.f) r1lo |= (1u << j); }
        else        { if (z1 > 0.f) r1hi |= (1u << (j - 32)); }
        acc[j] = fmaxf(z1, 0.f);
    }

    // ---- phase B1: z2_j = (h . W2T[j][:]) + b2_j; sign bits only.
    // Outer real loop over 16 groups of 4 j's; each j = one single-scalar
    // ascending-i fmaf chain (h = acc[], static inner index). 4 indep chains.
    unsigned r2lo = 0u, r2hi = 0u;
#pragma unroll 1
    for (int jg = 0; jg < NH / 4; ++jg) {
        const float* __restrict__ q0 = W2T + (jg * 4 + 0) * NH;  // uniform rows
        const float* __restrict__ q1 = W2T + (jg * 4 + 1) * NH;
        const float* __restrict__ q2 = W2T + (jg * 4 + 2) * NH;
        const float* __restrict__ q3 = W2T + (jg * 4 + 3) * NH;
        float p0 = 0.f, p1 = 0.f, p2 = 0.f, p3 = 0.f;
#pragma unroll
        for (int i = 0; i < NH; ++i) {
            p0 = fmaf(acc[i], q0[i], p0);
            p1 = fmaf(acc[i], q1[i], p1);
            p2 = fmaf(acc[i], q2[i], p2);
            p3 = fmaf(acc[i], q3[i], p3);
        }
        const int j0 = jg * 4;
        unsigned bits = 0u;
        if (p0 + b2[j0 + 0] > 0.f) bits |= 1u;
        if (p1 + b2[j0 + 1] > 0.f) bits |= 2u;
        if (p2 + b2[j0 + 2] > 0.f) bits |= 4u;
        if (p3 + b2[j0 + 3] > 0.f) bits |= 8u;
        if (j0 < 32) r2lo |= bits << j0; else r2hi |= bits << (j0 - 32);
    }
    // h (acc) dead after B1.

    // ---- phase B2 (values): t_j = sum_{j2 in r2} w3_j2 * W2T[j2][j] ----
    float t_[NH];
#pragma unroll
    for (int j = 0; j < NH; ++j) t_[j] = 0.f;

#pragma unroll 1
    for (int j2 = 0; j2 < NH; ++j2) {
        const bool mb = (j2 < 32) ? ((r2lo >> j2) & 1u) : ((r2hi >> (j2 - 32)) & 1u);
        const float ms = mb ? W3[j2] : 0.f;
        const float* __restrict__ wr = W2T + j2 * NH;            // uniform row
#pragma unroll
        for (int j = 0; j < NH; ++j) t_[j] = fmaf(ms, wr[j], t_[j]);
    }

    // u = r1 .* t (in place, static indices)
#pragma unroll
    for (int j = 0; j < NH; ++j) {
        const bool mb = (j < 32) ? ((r1lo >> j) & 1u) : ((r1hi >> (j - 32)) & 1u);
        t_[j] = mb ? t_[j] : 0.f;
    }

    // ---- phase C (values): out_k = -(W1 row k) . u, k outer loop, 4 chains.
    float* __restrict__ op = out + (size_t)s * ND;
#pragma unroll 1
    for (int kq = 0; kq < ND / 4; ++kq) {
        const float* __restrict__ w0 = W1 + (kq * 4 + 0) * NH;   // uniform rows
        const float* __restrict__ w1 = W1 + (kq * 4 + 1) * NH;
        const float* __restrict__ w2 = W1 + (kq * 4 + 2) * NH;
        const float* __restrict__ w3r = W1 + (kq * 4 + 3) * NH;
        float a0 = 0.f, a1 = 0.f, a2 = 0.f, a3 = 0.f;
#pragma unroll
        for (int i = 0; i < NH; ++i) {
            a0 = fmaf(w0[i],  t_[i], a0);
            a1 = fmaf(w1[i],  t_[i], a1);
            a2 = fmaf(w2[i],  t_[i], a2);
            a3 = fmaf(w3r[i], t_[i], a3);
        }
        float4 ov;
        ov.x = -a0; ov.y = -a1; ov.z = -a2; ov.w = -a3;
        reinterpret_cast<float4*>(op)[kq] = ov;
    }
}

extern "C" void kernel_launch(void* const* d_in, const int* in_sizes, int n_in,
                              void* d_out, int out_size, void* d_ws, size_t ws_size,
                              hipStream_t stream) {
    const float* X  = (const float*)d_in[0];
    const float* W1 = (const float*)d_in[1];
    const float* b1 = (const float*)d_in[2];
    const float* W2 = (const float*)d_in[3];
    const float* b2 = (const float*)d_in[4];
    const float* W3 = (const float*)d_in[5];
    // d_in[6] = b3: does not affect gradients.
    float* out = (float*)d_out;

    float* W2T = (float*)d_ws;            // 16384 B

    lnn_prep<<<16, 256, 0, stream>>>(W2, W2T);
    lnn_main<<<BATCH / TPB, TPB, 0, stream>>>(X, W1, b1, W2T, b2, W3, out);
}